// Round 11
// baseline (51.236 us; speedup 1.0000x reference)
//
#include <hip/hip_runtime.h>
#include <hip/hip_bf16.h>
#include <math.h>

// ComplexEMA via per-chunk Toeplitz MFMA + truncated-carry gather.
//   Kernel 1 (prep): per-d T/G/V MFMA A-fragments + q^32 per-mode -> ws.
//     Power table computed DIRECTLY per (n,j) thread as exp(j log r)*e^{ij phi}
//     (the reference's own formula) — no serial chain.
//   Kernel 2 (main): ONE BLOCK PER d, 8 waves = 8 batch rows, VGPR<=64 so
//     grid 1024 = exactly 4 blocks/CU -> whole grid co-resident, single
//     generation. E = V*X (8 MFMAs) -> LDS; carry C_c = sum_{k=1..4}
//     w^{k-1} E_{c-k} with RUNNING weight (16 regs, not 24);
//     Y = (T+wI)*X + G*C (16 MFMAs); sector-dense stores.
// R10 post-mortem: VGPR=68 > 64 meant 3 blocks/CU -> 1.33 generations.
// Lessons: R2 min-waves only when live-set fits (est ~58 now); R4
// sector-complete stores; R7 scan was DS-bound (gather); R8 one generation.

#define Bc 8
#define Dc 1024
#define Lc 2048
#define FRAG_STRIDE 6144                 // 3 mats * 2 rt * 64 lanes * 16B
#define SCANW_OFF (Dc * FRAG_STRIDE)     // then [d][16] float2 (128B per d)
#define ECS 18                           // EC column stride in words

typedef _Float16 f16x8 __attribute__((ext_vector_type(8)));
typedef __fp16 h16x2 __attribute__((ext_vector_type(2)));
typedef float f32x4 __attribute__((ext_vector_type(4)));

__device__ inline uint pkh(float a, float b) {
    h16x2 p = __builtin_amdgcn_cvt_pkrtz(a, b);
    union { h16x2 v; uint u; } c; c.v = p;
    return c.u;
}

__device__ inline float2 upk(uint u) {
    union { uint v; __fp16 h[2]; } p; p.v = u;
    return make_float2((float)p.h[0], (float)p.h[1]);
}

__device__ inline f16x8 cvt8(float4 a, float4 b) {
    union { h16x2 h[4]; f16x8 v; } r;
    r.h[0] = __builtin_amdgcn_cvt_pkrtz(a.x, a.y);
    r.h[1] = __builtin_amdgcn_cvt_pkrtz(a.z, a.w);
    r.h[2] = __builtin_amdgcn_cvt_pkrtz(b.x, b.y);
    r.h[3] = __builtin_amdgcn_cvt_pkrtz(b.z, b.w);
    return r.v;
}

__global__ __launch_bounds__(512) void prep_kernel(const float* __restrict__ alpha,
        const float* __restrict__ delta, const float* __restrict__ theta,
        const float* __restrict__ gamma_r, const float* __restrict__ gamma_i,
        const float* __restrict__ omega, char* __restrict__ ws) {
    __shared__ float qpr[16 * 33];
    __shared__ float qpi[16 * 33];
    __shared__ float gprs[16], gpis[16], kap[33];
    const int tid = threadIdx.x;
    const int d = blockIdx.x;

    // ---- parallel power table: thread (n, j) computes q_n^j directly
    {
        int n = tid >> 5;                // 0..15
        int j = (tid & 31) + 1;          // 1..32
        int idx = d * 16 + n;
        float a  = 1.f / (1.f + __expf(-alpha[idx]));
        float dl = 1.f / (1.f + __expf(-delta[idx]));
        float th = (1.f / (1.f + __expf(-theta[d]))) * (6.283185307179586f / 16.f);
        float phi = (float)(n + 1) * th;
        float radius = fminf(1.f - a * dl, 1.f);
        float rj = __expf((float)j * __logf(radius));   // == reference's decay
        float sn, cs; __sincosf((float)j * phi, &sn, &cs);
        qpr[n * 33 + j] = rj * cs;
        qpi[n * 33 + j] = rj * sn;
        if (j == 1) {
            qpr[n * 33] = 1.f; qpi[n * 33] = 0.f;
            gprs[n] = gamma_r[idx] * 0.25f * a;
            gpis[n] = gamma_i[idx] * 0.25f * a;
        }
    }
    __syncthreads();
    if (tid < 33) {
        float s = 0.f;
        #pragma unroll
        for (int n = 0; n < 16; ++n)
            s += gprs[n] * qpr[n * 33 + tid] - gpis[n] * qpi[n * 33 + tid];
        if (tid == 0) s += omega[d];
        kap[tid] = s;
    }
    __syncthreads();
    if (tid < 384) {
        int mat = tid >> 7;              // 0:T 1:G 2:V
        int sub = tid & 127;
        int rt = sub >> 6, ll = sub & 63;
        int row = rt * 16 + (ll & 15);
        int kb = 8 * (ll >> 4);
        union { _Float16 h[8]; f16x8 v; } fr;
        if (mat == 0) {
            #pragma unroll
            for (int j = 0; j < 8; ++j) {
                int dlt = row - (kb + j);
                fr.h[j] = (_Float16)((dlt >= 0) ? kap[dlt] : 0.f);
            }
        } else if (mat == 1) {
            #pragma unroll
            for (int j = 0; j < 8; ++j) {
                int k = kb + j, n = k >> 1;
                float qr_ = qpr[n * 33 + row + 1], qi_ = qpi[n * 33 + row + 1];
                float gr = gprs[n], gi = gpis[n];
                fr.h[j] = (_Float16)((k & 1) ? -(gr * qi_ + gi * qr_)
                                             : (gr * qr_ - gi * qi_));
            }
        } else {
            int n = row >> 1, im = row & 1;
            #pragma unroll
            for (int j = 0; j < 8; ++j) {
                int mm = kb + j;
                fr.h[j] = (_Float16)(im ? qpi[n * 33 + 31 - mm] : qpr[n * 33 + 31 - mm]);
            }
        }
        *(f16x8*)(ws + (size_t)d * FRAG_STRIDE + mat * 2048 + (rt * 64 + ll) * 16) = fr.v;
    } else if (tid < 400) {
        int n = tid - 384;
        float2* sw = (float2*)(ws + SCANW_OFF);
        sw[d * 16 + n] = make_float2(qpr[n * 33 + 32], qpi[n * 33 + 32]);
    }
}

__global__ __launch_bounds__(512, 8) void ema_main(const float* __restrict__ x,
        const char* __restrict__ ws, float* __restrict__ out) {
    __shared__ uint ECall[8 * 64 * ECS];     // 36,864B: 8 waves x 4.5KB
    const int tid = threadIdx.x;
    const int w = tid >> 6;                  // wave = batch row b
    const int l = tid & 63;
    const int d = blockIdx.x;
    uint* EC = ECall + w * (64 * ECS);
    const int g = l >> 4;
    const int m = l & 15;
    const size_t rowoff = ((size_t)w * Dc + d) * Lc;
    const float4* xr4 = (const float4*)(x + rowoff);
    const f16x8* fr = (const f16x8*)(ws + (size_t)d * FRAG_STRIDE);

    // ---- X B-fragments direct from global (col=m, k=8g+j within tile)
    f16x8 xf0, xf1, xf2, xf3;
    {
        const int base = m * 8 + 2 * g;
        float4 a0 = xr4[base],       b0 = xr4[base + 1];
        float4 a1 = xr4[base + 128], b1 = xr4[base + 129];
        float4 a2 = xr4[base + 256], b2 = xr4[base + 257];
        float4 a3 = xr4[base + 384], b3 = xr4[base + 385];
        xf0 = cvt8(a0, b0); xf1 = cvt8(a1, b1);
        xf2 = cvt8(a2, b2); xf3 = cvt8(a3, b3);
    }

    // ---- E = V*X (chunk end-states), pack f16 pairs into EC
    //      word W (=0..15) at column c holds complex E_c[mode W]
    {
        f16x8 va0 = fr[256 + l], va1 = fr[320 + l];
        #define EMFMA(VA, RT, TC, XF) { \
            f32x4 acc = {0.f, 0.f, 0.f, 0.f}; \
            acc = __builtin_amdgcn_mfma_f32_16x16x32_f16(VA, XF, acc, 0, 0, 0); \
            uint2 u; u.x = pkh(acc[0], acc[1]); u.y = pkh(acc[2], acc[3]); \
            *(uint2*)&EC[(TC * 16 + m) * ECS + 8 * RT + 2 * g] = u; }
        EMFMA(va0, 0, 0, xf0) EMFMA(va0, 0, 1, xf1)
        EMFMA(va0, 0, 2, xf2) EMFMA(va0, 0, 3, xf3)
        EMFMA(va1, 1, 0, xf0) EMFMA(va1, 1, 1, xf1)
        EMFMA(va1, 1, 2, xf2) EMFMA(va1, 1, 3, xf3)
        #undef EMFMA
    }

    // ---- issue w1 / T / G loads now; pre-barrier vmcnt drain hides latency
    float w1r[4], w1i[4];
    {
        const float2* sw = (const float2*)(ws + SCANW_OFF + (size_t)d * 128);
        #pragma unroll
        for (int j = 0; j < 4; ++j) {
            float2 t = sw[4 * g + j];
            w1r[j] = t.x; w1i[j] = t.y;
        }
    }
    f16x8 ta0 = fr[l],       ta1 = fr[64 + l];
    f16x8 ga0 = fr[128 + l], ga1 = fr[192 + l];

    __syncthreads();                     // single barrier: E visible

    // ---- per tile: build C fragment in registers (truncated carry,
    //      RUNNING weight wk = w^(k-1)), then Y = (T+wI)*X + G*C
    float4* or4 = (float4*)(out + rowoff);

    #pragma unroll
    for (int tc = 0; tc < 4; ++tc) {
        f16x8 xf = (tc == 0) ? xf0 : (tc == 1) ? xf1 : (tc == 2) ? xf2 : xf3;
        float cr_[4] = {0.f, 0.f, 0.f, 0.f};
        float ci_[4] = {0.f, 0.f, 0.f, 0.f};
        float kr[4] = {1.f, 1.f, 1.f, 1.f};
        float ki[4] = {0.f, 0.f, 0.f, 0.f};
        #pragma unroll
        for (int k = 1; k <= 4; ++k) {
            int c2 = tc * 16 + m - k;
            int cc = (c2 < 0) ? 0 : c2;
            uint2 e0 = *(const uint2*)&EC[cc * ECS + 4 * g];
            uint2 e1 = *(const uint2*)&EC[cc * ECS + 4 * g + 2];
            if (c2 >= 0) {
                float2 aa[4] = { upk(e0.x), upk(e0.y), upk(e1.x), upk(e1.y) };
                #pragma unroll
                for (int j = 0; j < 4; ++j) {
                    cr_[j] = fmaf(kr[j], aa[j].x, fmaf(-ki[j], aa[j].y, cr_[j]));
                    ci_[j] = fmaf(kr[j], aa[j].y, fmaf( ki[j], aa[j].x, ci_[j]));
                }
            }
            if (k < 4) {
                #pragma unroll
                for (int j = 0; j < 4; ++j) {
                    float t2 = fmaf(kr[j], w1r[j], -(ki[j] * w1i[j]));
                    ki[j] = fmaf(kr[j], w1i[j], ki[j] * w1r[j]);
                    kr[j] = t2;
                }
            }
        }
        union { h16x2 h[4]; f16x8 v; } cb;
        #pragma unroll
        for (int j = 0; j < 4; ++j)
            cb.h[j] = __builtin_amdgcn_cvt_pkrtz(cr_[j], ci_[j]);
        f32x4 y0 = {0.f, 0.f, 0.f, 0.f}, y1 = {0.f, 0.f, 0.f, 0.f};
        y0 = __builtin_amdgcn_mfma_f32_16x16x32_f16(ta0, xf,   y0, 0, 0, 0);
        y0 = __builtin_amdgcn_mfma_f32_16x16x32_f16(ga0, cb.v, y0, 0, 0, 0);
        y1 = __builtin_amdgcn_mfma_f32_16x16x32_f16(ta1, xf,   y1, 0, 0, 0);
        y1 = __builtin_amdgcn_mfma_f32_16x16x32_f16(ga1, cb.v, y1, 0, 0, 0);
        float4 o0, o1;
        o0.x = y0[0]; o0.y = y0[1]; o0.z = y0[2]; o0.w = y0[3];
        o1.x = y1[0]; o1.y = y1[1]; o1.z = y1[2]; o1.w = y1[3];
        or4[(tc * 16 + m) * 8 + g]     = o0;
        or4[(tc * 16 + m) * 8 + 4 + g] = o1;
    }
}

extern "C" void kernel_launch(void* const* d_in, const int* in_sizes, int n_in,
                              void* d_out, int out_size, void* d_ws, size_t ws_size,
                              hipStream_t stream) {
    const float* x       = (const float*)d_in[0];
    const float* alpha   = (const float*)d_in[1];
    const float* delta   = (const float*)d_in[2];
    const float* theta   = (const float*)d_in[3];
    const float* gamma_r = (const float*)d_in[4];
    const float* gamma_i = (const float*)d_in[5];
    const float* omega   = (const float*)d_in[6];
    float* out = (float*)d_out;
    // ws usage: 1024*6144 + 1024*128 = 6,422,528 bytes
    char* ws = (char*)d_ws;

    prep_kernel<<<Dc, 512, 0, stream>>>(alpha, delta, theta,
                                        gamma_r, gamma_i, omega, ws);
    ema_main<<<Dc, 512, 0, stream>>>(x, ws, out);
}

// Round 12
// 34.341 us; speedup vs baseline: 1.4920x; 1.4920x over previous
//
#include <hip/hip_runtime.h>
#include <hip/hip_bf16.h>
#include <math.h>

// ComplexEMA via per-chunk Toeplitz MFMA + truncated-carry gather.
//   Kernel 1 (prep): per-d T/G/V MFMA A-fragments + q^32 per-mode -> ws.
//     Power table computed DIRECTLY per (n,j) thread (no serial chain).
//   Kernel 2 (main): ONE BLOCK PER d, 8 waves = 8 batch rows.
//     E = V*X (8 MFMAs) -> LDS (stride-18 cols: 0 bank conflicts measured);
//     carry C_c = sum_{k=1..4} w^{k-1} E_{c-k} with RUNNING weight;
//     Y = (T+wI)*X + G*C (16 MFMAs); sector-dense stores.
// R11 post-mortem: __launch_bounds__(512,8) clamped VGPR to 32 << ~56 live
//   -> spill (FETCH 39->76MB, WRITE 65->117MB, dur 43->73us). NEVER set
//   min-waves to force occupancy below the live set (R2, R11). Let the
//   allocator pick; trim live set manually if >64.
// Lessons: R4 sector-complete stores; R7 gather not scan; R8 co-residency.

#define Bc 8
#define Dc 1024
#define Lc 2048
#define FRAG_STRIDE 6144                 // 3 mats * 2 rt * 64 lanes * 16B
#define SCANW_OFF (Dc * FRAG_STRIDE)     // then [d][16] float2 (128B per d)
#define ECS 18                           // EC column stride in words

typedef _Float16 f16x8 __attribute__((ext_vector_type(8)));
typedef __fp16 h16x2 __attribute__((ext_vector_type(2)));
typedef float f32x4 __attribute__((ext_vector_type(4)));

__device__ inline uint pkh(float a, float b) {
    h16x2 p = __builtin_amdgcn_cvt_pkrtz(a, b);
    union { h16x2 v; uint u; } c; c.v = p;
    return c.u;
}

__device__ inline float2 upk(uint u) {
    union { uint v; __fp16 h[2]; } p; p.v = u;
    return make_float2((float)p.h[0], (float)p.h[1]);
}

__device__ inline f16x8 cvt8(float4 a, float4 b) {
    union { h16x2 h[4]; f16x8 v; } r;
    r.h[0] = __builtin_amdgcn_cvt_pkrtz(a.x, a.y);
    r.h[1] = __builtin_amdgcn_cvt_pkrtz(a.z, a.w);
    r.h[2] = __builtin_amdgcn_cvt_pkrtz(b.x, b.y);
    r.h[3] = __builtin_amdgcn_cvt_pkrtz(b.z, b.w);
    return r.v;
}

__global__ __launch_bounds__(512) void prep_kernel(const float* __restrict__ alpha,
        const float* __restrict__ delta, const float* __restrict__ theta,
        const float* __restrict__ gamma_r, const float* __restrict__ gamma_i,
        const float* __restrict__ omega, char* __restrict__ ws) {
    __shared__ float qpr[16 * 33];
    __shared__ float qpi[16 * 33];
    __shared__ float gprs[16], gpis[16], kap[33];
    const int tid = threadIdx.x;
    const int d = blockIdx.x;

    // ---- parallel power table: thread (n, j) computes q_n^j directly
    {
        int n = tid >> 5;                // 0..15
        int j = (tid & 31) + 1;          // 1..32
        int idx = d * 16 + n;
        float a  = 1.f / (1.f + __expf(-alpha[idx]));
        float dl = 1.f / (1.f + __expf(-delta[idx]));
        float th = (1.f / (1.f + __expf(-theta[d]))) * (6.283185307179586f / 16.f);
        float phi = (float)(n + 1) * th;
        float radius = fminf(1.f - a * dl, 1.f);
        float rj = __expf((float)j * __logf(radius));   // == reference's decay
        float sn, cs; __sincosf((float)j * phi, &sn, &cs);
        qpr[n * 33 + j] = rj * cs;
        qpi[n * 33 + j] = rj * sn;
        if (j == 1) {
            qpr[n * 33] = 1.f; qpi[n * 33] = 0.f;
            gprs[n] = gamma_r[idx] * 0.25f * a;
            gpis[n] = gamma_i[idx] * 0.25f * a;
        }
    }
    __syncthreads();
    if (tid < 33) {
        float s = 0.f;
        #pragma unroll
        for (int n = 0; n < 16; ++n)
            s += gprs[n] * qpr[n * 33 + tid] - gpis[n] * qpi[n * 33 + tid];
        if (tid == 0) s += omega[d];
        kap[tid] = s;
    }
    __syncthreads();
    if (tid < 384) {
        int mat = tid >> 7;              // 0:T 1:G 2:V
        int sub = tid & 127;
        int rt = sub >> 6, ll = sub & 63;
        int row = rt * 16 + (ll & 15);
        int kb = 8 * (ll >> 4);
        union { _Float16 h[8]; f16x8 v; } fr;
        if (mat == 0) {
            #pragma unroll
            for (int j = 0; j < 8; ++j) {
                int dlt = row - (kb + j);
                fr.h[j] = (_Float16)((dlt >= 0) ? kap[dlt] : 0.f);
            }
        } else if (mat == 1) {
            #pragma unroll
            for (int j = 0; j < 8; ++j) {
                int k = kb + j, n = k >> 1;
                float qr_ = qpr[n * 33 + row + 1], qi_ = qpi[n * 33 + row + 1];
                float gr = gprs[n], gi = gpis[n];
                fr.h[j] = (_Float16)((k & 1) ? -(gr * qi_ + gi * qr_)
                                             : (gr * qr_ - gi * qi_));
            }
        } else {
            int n = row >> 1, im = row & 1;
            #pragma unroll
            for (int j = 0; j < 8; ++j) {
                int mm = kb + j;
                fr.h[j] = (_Float16)(im ? qpi[n * 33 + 31 - mm] : qpr[n * 33 + 31 - mm]);
            }
        }
        *(f16x8*)(ws + (size_t)d * FRAG_STRIDE + mat * 2048 + (rt * 64 + ll) * 16) = fr.v;
    } else if (tid < 400) {
        int n = tid - 384;
        float2* sw = (float2*)(ws + SCANW_OFF);
        sw[d * 16 + n] = make_float2(qpr[n * 33 + 32], qpi[n * 33 + 32]);
    }
}

__global__ __launch_bounds__(512) void ema_main(const float* __restrict__ x,
        const char* __restrict__ ws, float* __restrict__ out) {
    __shared__ uint ECall[8 * 64 * ECS];     // 36,864B: 8 waves x 4.5KB
    const int tid = threadIdx.x;
    const int w = tid >> 6;                  // wave = batch row b
    const int l = tid & 63;
    const int d = blockIdx.x;
    uint* EC = ECall + w * (64 * ECS);
    const int g = l >> 4;
    const int m = l & 15;
    const size_t rowoff = ((size_t)w * Dc + d) * Lc;
    const float4* xr4 = (const float4*)(x + rowoff);
    const f16x8* fr = (const f16x8*)(ws + (size_t)d * FRAG_STRIDE);

    // ---- X B-fragments direct from global (col=m, k=8g+j within tile)
    f16x8 xf0, xf1, xf2, xf3;
    {
        const int base = m * 8 + 2 * g;
        float4 a0 = xr4[base],       b0 = xr4[base + 1];
        float4 a1 = xr4[base + 128], b1 = xr4[base + 129];
        float4 a2 = xr4[base + 256], b2 = xr4[base + 257];
        float4 a3 = xr4[base + 384], b3 = xr4[base + 385];
        xf0 = cvt8(a0, b0); xf1 = cvt8(a1, b1);
        xf2 = cvt8(a2, b2); xf3 = cvt8(a3, b3);
    }

    // ---- E = V*X (chunk end-states), pack f16 pairs into EC
    //      word W (=0..15) at column c holds complex E_c[mode W]
    {
        f16x8 va0 = fr[256 + l], va1 = fr[320 + l];
        #define EMFMA(VA, RT, TC, XF) { \
            f32x4 acc = {0.f, 0.f, 0.f, 0.f}; \
            acc = __builtin_amdgcn_mfma_f32_16x16x32_f16(VA, XF, acc, 0, 0, 0); \
            uint2 u; u.x = pkh(acc[0], acc[1]); u.y = pkh(acc[2], acc[3]); \
            *(uint2*)&EC[(TC * 16 + m) * ECS + 8 * RT + 2 * g] = u; }
        EMFMA(va0, 0, 0, xf0) EMFMA(va0, 0, 1, xf1)
        EMFMA(va0, 0, 2, xf2) EMFMA(va0, 0, 3, xf3)
        EMFMA(va1, 1, 0, xf0) EMFMA(va1, 1, 1, xf1)
        EMFMA(va1, 1, 2, xf2) EMFMA(va1, 1, 3, xf3)
        #undef EMFMA
    }

    // ---- issue w1 / T / G loads now; pre-barrier vmcnt drain hides latency
    float w1r[4], w1i[4];
    {
        const float2* sw = (const float2*)(ws + SCANW_OFF + (size_t)d * 128);
        #pragma unroll
        for (int j = 0; j < 4; ++j) {
            float2 t = sw[4 * g + j];
            w1r[j] = t.x; w1i[j] = t.y;
        }
    }
    f16x8 ta0 = fr[l],       ta1 = fr[64 + l];
    f16x8 ga0 = fr[128 + l], ga1 = fr[192 + l];

    __syncthreads();                     // single barrier: E visible

    // ---- per tile: build C fragment in registers (truncated carry,
    //      RUNNING weight wk = w^(k-1)), then Y = (T+wI)*X + G*C
    float4* or4 = (float4*)(out + rowoff);

    #pragma unroll
    for (int tc = 0; tc < 4; ++tc) {
        f16x8 xf = (tc == 0) ? xf0 : (tc == 1) ? xf1 : (tc == 2) ? xf2 : xf3;
        float cr_[4] = {0.f, 0.f, 0.f, 0.f};
        float ci_[4] = {0.f, 0.f, 0.f, 0.f};
        float kr[4] = {1.f, 1.f, 1.f, 1.f};
        float ki[4] = {0.f, 0.f, 0.f, 0.f};
        #pragma unroll
        for (int k = 1; k <= 4; ++k) {
            int c2 = tc * 16 + m - k;
            int cc = (c2 < 0) ? 0 : c2;
            uint2 e0 = *(const uint2*)&EC[cc * ECS + 4 * g];
            uint2 e1 = *(const uint2*)&EC[cc * ECS + 4 * g + 2];
            if (c2 >= 0) {
                float2 aa[4] = { upk(e0.x), upk(e0.y), upk(e1.x), upk(e1.y) };
                #pragma unroll
                for (int j = 0; j < 4; ++j) {
                    cr_[j] = fmaf(kr[j], aa[j].x, fmaf(-ki[j], aa[j].y, cr_[j]));
                    ci_[j] = fmaf(kr[j], aa[j].y, fmaf( ki[j], aa[j].x, ci_[j]));
                }
            }
            if (k < 4) {
                #pragma unroll
                for (int j = 0; j < 4; ++j) {
                    float t2 = fmaf(kr[j], w1r[j], -(ki[j] * w1i[j]));
                    ki[j] = fmaf(kr[j], w1i[j], ki[j] * w1r[j]);
                    kr[j] = t2;
                }
            }
        }
        union { h16x2 h[4]; f16x8 v; } cb;
        #pragma unroll
        for (int j = 0; j < 4; ++j)
            cb.h[j] = __builtin_amdgcn_cvt_pkrtz(cr_[j], ci_[j]);
        f32x4 y0 = {0.f, 0.f, 0.f, 0.f}, y1 = {0.f, 0.f, 0.f, 0.f};
        y0 = __builtin_amdgcn_mfma_f32_16x16x32_f16(ta0, xf,   y0, 0, 0, 0);
        y0 = __builtin_amdgcn_mfma_f32_16x16x32_f16(ga0, cb.v, y0, 0, 0, 0);
        y1 = __builtin_amdgcn_mfma_f32_16x16x32_f16(ta1, xf,   y1, 0, 0, 0);
        y1 = __builtin_amdgcn_mfma_f32_16x16x32_f16(ga1, cb.v, y1, 0, 0, 0);
        float4 o0, o1;
        o0.x = y0[0]; o0.y = y0[1]; o0.z = y0[2]; o0.w = y0[3];
        o1.x = y1[0]; o1.y = y1[1]; o1.z = y1[2]; o1.w = y1[3];
        or4[(tc * 16 + m) * 8 + g]     = o0;
        or4[(tc * 16 + m) * 8 + 4 + g] = o1;
    }
}

extern "C" void kernel_launch(void* const* d_in, const int* in_sizes, int n_in,
                              void* d_out, int out_size, void* d_ws, size_t ws_size,
                              hipStream_t stream) {
    const float* x       = (const float*)d_in[0];
    const float* alpha   = (const float*)d_in[1];
    const float* delta   = (const float*)d_in[2];
    const float* theta   = (const float*)d_in[3];
    const float* gamma_r = (const float*)d_in[4];
    const float* gamma_i = (const float*)d_in[5];
    const float* omega   = (const float*)d_in[6];
    float* out = (float*)d_out;
    // ws usage: 1024*6144 + 1024*128 = 6,422,528 bytes
    char* ws = (char*)d_ws;

    prep_kernel<<<Dc, 512, 0, stream>>>(alpha, delta, theta,
                                        gamma_r, gamma_i, omega, ws);
    ema_main<<<Dc, 512, 0, stream>>>(x, ws, out);
}

// Round 13
// 33.490 us; speedup vs baseline: 1.5299x; 1.0254x over previous
//
#include <hip/hip_runtime.h>
#include <hip/hip_bf16.h>
#include <math.h>

// ComplexEMA via per-chunk Toeplitz MFMA + truncated-carry gather.
//   Kernel 1 (prep): per-d T/G/V MFMA A-fragments + q^32 per-mode -> ws.
//     Power table computed DIRECTLY per (n,j) thread (no serial chain).
//   Kernel 2 (main): ONE BLOCK PER d, 8 waves = 8 batch rows.
//     E = V*X (8 MFMAs) -> wave-PRIVATE LDS slice (stride-18 cols, 0 bank
//     conflicts); carry C_c = sum_{k=1..4} w^{k-1} E_{c-k} running-weight
//     gather; Y = (T+wI)*X + G*C (16 MFMAs); sector-dense stores.
//   R13: NO __syncthreads in main. EC slices are wave-private; same-wave
//     ds_write->ds_read ordering is guaranteed by lgkmcnt (compiler-
//     inserted, accesses alias). Barrier only forced 8-wave lockstep
//     convoy. wave_barrier() = compiler fence, no hw cost.
// R11 post-mortem: NEVER min-waves below live set (VGPR clamp -> spill).
// Lessons: R4 sector-complete stores; R7 gather not scan; R8 co-residency.

#define Bc 8
#define Dc 1024
#define Lc 2048
#define FRAG_STRIDE 6144                 // 3 mats * 2 rt * 64 lanes * 16B
#define SCANW_OFF (Dc * FRAG_STRIDE)     // then [d][16] float2 (128B per d)
#define ECS 18                           // EC column stride in words

typedef _Float16 f16x8 __attribute__((ext_vector_type(8)));
typedef __fp16 h16x2 __attribute__((ext_vector_type(2)));
typedef float f32x4 __attribute__((ext_vector_type(4)));

__device__ inline uint pkh(float a, float b) {
    h16x2 p = __builtin_amdgcn_cvt_pkrtz(a, b);
    union { h16x2 v; uint u; } c; c.v = p;
    return c.u;
}

__device__ inline float2 upk(uint u) {
    union { uint v; __fp16 h[2]; } p; p.v = u;
    return make_float2((float)p.h[0], (float)p.h[1]);
}

__device__ inline f16x8 cvt8(float4 a, float4 b) {
    union { h16x2 h[4]; f16x8 v; } r;
    r.h[0] = __builtin_amdgcn_cvt_pkrtz(a.x, a.y);
    r.h[1] = __builtin_amdgcn_cvt_pkrtz(a.z, a.w);
    r.h[2] = __builtin_amdgcn_cvt_pkrtz(b.x, b.y);
    r.h[3] = __builtin_amdgcn_cvt_pkrtz(b.z, b.w);
    return r.v;
}

__global__ __launch_bounds__(512) void prep_kernel(const float* __restrict__ alpha,
        const float* __restrict__ delta, const float* __restrict__ theta,
        const float* __restrict__ gamma_r, const float* __restrict__ gamma_i,
        const float* __restrict__ omega, char* __restrict__ ws) {
    __shared__ float qpr[16 * 33];
    __shared__ float qpi[16 * 33];
    __shared__ float gprs[16], gpis[16], kap[33];
    const int tid = threadIdx.x;
    const int d = blockIdx.x;

    // ---- parallel power table: thread (n, j) computes q_n^j directly
    {
        int n = tid >> 5;                // 0..15
        int j = (tid & 31) + 1;          // 1..32
        int idx = d * 16 + n;
        float a  = 1.f / (1.f + __expf(-alpha[idx]));
        float dl = 1.f / (1.f + __expf(-delta[idx]));
        float th = (1.f / (1.f + __expf(-theta[d]))) * (6.283185307179586f / 16.f);
        float phi = (float)(n + 1) * th;
        float radius = fminf(1.f - a * dl, 1.f);
        float rj = __expf((float)j * __logf(radius));   // == reference's decay
        float sn, cs; __sincosf((float)j * phi, &sn, &cs);
        qpr[n * 33 + j] = rj * cs;
        qpi[n * 33 + j] = rj * sn;
        if (j == 1) {
            qpr[n * 33] = 1.f; qpi[n * 33] = 0.f;
            gprs[n] = gamma_r[idx] * 0.25f * a;
            gpis[n] = gamma_i[idx] * 0.25f * a;
        }
    }
    __syncthreads();
    if (tid < 33) {
        float s = 0.f;
        #pragma unroll
        for (int n = 0; n < 16; ++n)
            s += gprs[n] * qpr[n * 33 + tid] - gpis[n] * qpi[n * 33 + tid];
        if (tid == 0) s += omega[d];
        kap[tid] = s;
    }
    __syncthreads();
    if (tid < 384) {
        int mat = tid >> 7;              // 0:T 1:G 2:V
        int sub = tid & 127;
        int rt = sub >> 6, ll = sub & 63;
        int row = rt * 16 + (ll & 15);
        int kb = 8 * (ll >> 4);
        union { _Float16 h[8]; f16x8 v; } fr;
        if (mat == 0) {
            #pragma unroll
            for (int j = 0; j < 8; ++j) {
                int dlt = row - (kb + j);
                fr.h[j] = (_Float16)((dlt >= 0) ? kap[dlt] : 0.f);
            }
        } else if (mat == 1) {
            #pragma unroll
            for (int j = 0; j < 8; ++j) {
                int k = kb + j, n = k >> 1;
                float qr_ = qpr[n * 33 + row + 1], qi_ = qpi[n * 33 + row + 1];
                float gr = gprs[n], gi = gpis[n];
                fr.h[j] = (_Float16)((k & 1) ? -(gr * qi_ + gi * qr_)
                                             : (gr * qr_ - gi * qi_));
            }
        } else {
            int n = row >> 1, im = row & 1;
            #pragma unroll
            for (int j = 0; j < 8; ++j) {
                int mm = kb + j;
                fr.h[j] = (_Float16)(im ? qpi[n * 33 + 31 - mm] : qpr[n * 33 + 31 - mm]);
            }
        }
        *(f16x8*)(ws + (size_t)d * FRAG_STRIDE + mat * 2048 + (rt * 64 + ll) * 16) = fr.v;
    } else if (tid < 400) {
        int n = tid - 384;
        float2* sw = (float2*)(ws + SCANW_OFF);
        sw[d * 16 + n] = make_float2(qpr[n * 33 + 32], qpi[n * 33 + 32]);
    }
}

__global__ __launch_bounds__(512) void ema_main(const float* __restrict__ x,
        const char* __restrict__ ws, float* __restrict__ out) {
    __shared__ uint ECall[8 * 64 * ECS];     // 36,864B: 8 waves x 4.5KB PRIVATE
    const int tid = threadIdx.x;
    const int w = tid >> 6;                  // wave = batch row b
    const int l = tid & 63;
    const int d = blockIdx.x;
    uint* EC = ECall + w * (64 * ECS);
    const int g = l >> 4;
    const int m = l & 15;
    const size_t rowoff = ((size_t)w * Dc + d) * Lc;
    const float4* xr4 = (const float4*)(x + rowoff);
    const f16x8* fr = (const f16x8*)(ws + (size_t)d * FRAG_STRIDE);

    // ---- X B-fragments direct from global (col=m, k=8g+j within tile)
    f16x8 xf0, xf1, xf2, xf3;
    {
        const int base = m * 8 + 2 * g;
        float4 a0 = xr4[base],       b0 = xr4[base + 1];
        float4 a1 = xr4[base + 128], b1 = xr4[base + 129];
        float4 a2 = xr4[base + 256], b2 = xr4[base + 257];
        float4 a3 = xr4[base + 384], b3 = xr4[base + 385];
        xf0 = cvt8(a0, b0); xf1 = cvt8(a1, b1);
        xf2 = cvt8(a2, b2); xf3 = cvt8(a3, b3);
    }

    // ---- E = V*X (chunk end-states), pack f16 pairs into own EC slice
    //      word W (=0..15) at column c holds complex E_c[mode W]
    {
        f16x8 va0 = fr[256 + l], va1 = fr[320 + l];
        #define EMFMA(VA, RT, TC, XF) { \
            f32x4 acc = {0.f, 0.f, 0.f, 0.f}; \
            acc = __builtin_amdgcn_mfma_f32_16x16x32_f16(VA, XF, acc, 0, 0, 0); \
            uint2 u; u.x = pkh(acc[0], acc[1]); u.y = pkh(acc[2], acc[3]); \
            *(uint2*)&EC[(TC * 16 + m) * ECS + 8 * RT + 2 * g] = u; }
        EMFMA(va0, 0, 0, xf0) EMFMA(va0, 0, 1, xf1)
        EMFMA(va0, 0, 2, xf2) EMFMA(va0, 0, 3, xf3)
        EMFMA(va1, 1, 0, xf0) EMFMA(va1, 1, 1, xf1)
        EMFMA(va1, 1, 2, xf2) EMFMA(va1, 1, 3, xf3)
        #undef EMFMA
    }

    // ---- w1 / T / G loads (overlap with EC write drain)
    float w1r[4], w1i[4];
    {
        const float2* sw = (const float2*)(ws + SCANW_OFF + (size_t)d * 128);
        #pragma unroll
        for (int j = 0; j < 4; ++j) {
            float2 t = sw[4 * g + j];
            w1r[j] = t.x; w1i[j] = t.y;
        }
    }
    f16x8 ta0 = fr[l],       ta1 = fr[64 + l];
    f16x8 ga0 = fr[128 + l], ga1 = fr[192 + l];

    // NO __syncthreads: EC slice is wave-private; same-wave ds ordering is
    // guaranteed via lgkmcnt (accesses alias -> compiler keeps order).
    // wave_barrier = zero-cost compiler scheduling fence for insurance.
    __builtin_amdgcn_wave_barrier();

    // ---- per tile: build C fragment in registers (truncated carry,
    //      RUNNING weight wk = w^(k-1)), then Y = (T+wI)*X + G*C
    float4* or4 = (float4*)(out + rowoff);

    #pragma unroll
    for (int tc = 0; tc < 4; ++tc) {
        f16x8 xf = (tc == 0) ? xf0 : (tc == 1) ? xf1 : (tc == 2) ? xf2 : xf3;
        float cr_[4] = {0.f, 0.f, 0.f, 0.f};
        float ci_[4] = {0.f, 0.f, 0.f, 0.f};
        float kr[4] = {1.f, 1.f, 1.f, 1.f};
        float ki[4] = {0.f, 0.f, 0.f, 0.f};
        #pragma unroll
        for (int k = 1; k <= 4; ++k) {
            int c2 = tc * 16 + m - k;
            int cc = (c2 < 0) ? 0 : c2;
            uint2 e0 = *(const uint2*)&EC[cc * ECS + 4 * g];
            uint2 e1 = *(const uint2*)&EC[cc * ECS + 4 * g + 2];
            if (c2 >= 0) {
                float2 aa[4] = { upk(e0.x), upk(e0.y), upk(e1.x), upk(e1.y) };
                #pragma unroll
                for (int j = 0; j < 4; ++j) {
                    cr_[j] = fmaf(kr[j], aa[j].x, fmaf(-ki[j], aa[j].y, cr_[j]));
                    ci_[j] = fmaf(kr[j], aa[j].y, fmaf( ki[j], aa[j].x, ci_[j]));
                }
            }
            if (k < 4) {
                #pragma unroll
                for (int j = 0; j < 4; ++j) {
                    float t2 = fmaf(kr[j], w1r[j], -(ki[j] * w1i[j]));
                    ki[j] = fmaf(kr[j], w1i[j], ki[j] * w1r[j]);
                    kr[j] = t2;
                }
            }
        }
        union { h16x2 h[4]; f16x8 v; } cb;
        #pragma unroll
        for (int j = 0; j < 4; ++j)
            cb.h[j] = __builtin_amdgcn_cvt_pkrtz(cr_[j], ci_[j]);
        f32x4 y0 = {0.f, 0.f, 0.f, 0.f}, y1 = {0.f, 0.f, 0.f, 0.f};
        y0 = __builtin_amdgcn_mfma_f32_16x16x32_f16(ta0, xf,   y0, 0, 0, 0);
        y0 = __builtin_amdgcn_mfma_f32_16x16x32_f16(ga0, cb.v, y0, 0, 0, 0);
        y1 = __builtin_amdgcn_mfma_f32_16x16x32_f16(ta1, xf,   y1, 0, 0, 0);
        y1 = __builtin_amdgcn_mfma_f32_16x16x32_f16(ga1, cb.v, y1, 0, 0, 0);
        float4 o0, o1;
        o0.x = y0[0]; o0.y = y0[1]; o0.z = y0[2]; o0.w = y0[3];
        o1.x = y1[0]; o1.y = y1[1]; o1.z = y1[2]; o1.w = y1[3];
        or4[(tc * 16 + m) * 8 + g]     = o0;
        or4[(tc * 16 + m) * 8 + 4 + g] = o1;
    }
}

extern "C" void kernel_launch(void* const* d_in, const int* in_sizes, int n_in,
                              void* d_out, int out_size, void* d_ws, size_t ws_size,
                              hipStream_t stream) {
    const float* x       = (const float*)d_in[0];
    const float* alpha   = (const float*)d_in[1];
    const float* delta   = (const float*)d_in[2];
    const float* theta   = (const float*)d_in[3];
    const float* gamma_r = (const float*)d_in[4];
    const float* gamma_i = (const float*)d_in[5];
    const float* omega   = (const float*)d_in[6];
    float* out = (float*)d_out;
    // ws usage: 1024*6144 + 1024*128 = 6,422,528 bytes
    char* ws = (char*)d_ws;

    prep_kernel<<<Dc, 512, 0, stream>>>(alpha, delta, theta,
                                        gamma_r, gamma_i, omega, ws);
    ema_main<<<Dc, 512, 0, stream>>>(x, ws, out);
}

// Round 14
// 31.345 us; speedup vs baseline: 1.6346x; 1.0684x over previous
//
#include <hip/hip_runtime.h>
#include <hip/hip_bf16.h>
#include <math.h>

// ComplexEMA, single fused kernel. One block per d (grid 1024, 512 thr);
// 8 waves = 8 batch rows.
//   Phase A (all thr): q_n^j power table direct per (n,j) -> LDS (overlay).
//   Phase B (33 thr): kernel taps kap. Phase C (384 thr): T/G/V MFMA
//   A-fragments -> LDS. 3 cheap uniform barriers, all BEFORE the long
//   per-wave section (R13's barrier-free main loop preserved).
//   Per wave: E = V*X (8 MFMAs) -> wave-private LDS slice (stride 18, 0
//   conflicts); carry C_c = sum_{k=1..4} w^{k-1} E_{c-k} running-weight
//   gather; Y = (T+wI)*X + G*C (16 MFMAs); sector-dense stores.
//   x loads issued FIRST so HBM latency hides under phases A-C.
//   qpr/qpi table overlays the EC region (dead after phase C, barrier-sep).
// Post-mortems: R2/R11 never min-waves below live set (spill);
// R4 sector-complete stores; R7 gather not scan (DS-pipe); R13 EC slices
// wave-private -> no barrier in main section; R14 fuse to kill launch+ws.

#define Bc 8
#define Dc 1024
#define Lc 2048
#define ECS 18                           // EC column stride in words
#define TABW (16 * 33)

typedef _Float16 f16x8 __attribute__((ext_vector_type(8)));
typedef __fp16 h16x2 __attribute__((ext_vector_type(2)));
typedef float f32x4 __attribute__((ext_vector_type(4)));

__device__ inline uint pkh(float a, float b) {
    h16x2 p = __builtin_amdgcn_cvt_pkrtz(a, b);
    union { h16x2 v; uint u; } c; c.v = p;
    return c.u;
}

__device__ inline float2 upk(uint u) {
    union { uint v; __fp16 h[2]; } p; p.v = u;
    return make_float2((float)p.h[0], (float)p.h[1]);
}

__device__ inline f16x8 cvt8(float4 a, float4 b) {
    union { h16x2 h[4]; f16x8 v; } r;
    r.h[0] = __builtin_amdgcn_cvt_pkrtz(a.x, a.y);
    r.h[1] = __builtin_amdgcn_cvt_pkrtz(a.z, a.w);
    r.h[2] = __builtin_amdgcn_cvt_pkrtz(b.x, b.y);
    r.h[3] = __builtin_amdgcn_cvt_pkrtz(b.z, b.w);
    return r.v;
}

__global__ __launch_bounds__(512) void ema_fused(const float* __restrict__ x,
        const float* __restrict__ alpha, const float* __restrict__ delta,
        const float* __restrict__ theta, const float* __restrict__ gamma_r,
        const float* __restrict__ gamma_i, const float* __restrict__ omega,
        float* __restrict__ out) {
    __shared__ uint ECall[8 * 64 * ECS];     // 36,864B; overlays qpr/qpi
    __shared__ __align__(16) _Float16 fragH[384 * 8];   // 6KB: T,G,V frags
    __shared__ float kap[33], gprs[16], gpis[16];
    __shared__ float2 scanw[16];

    const int tid = threadIdx.x;
    const int d = blockIdx.x;
    const int w = tid >> 6;                  // wave = batch row b
    const int l = tid & 63;
    const int g = l >> 4;
    const int m = l & 15;

    float* qpr = (float*)ECall;              // overlay (dead after phase C)
    float* qpi = qpr + TABW;
    const f16x8* frag = (const f16x8*)fragH;

    // ---- issue x loads FIRST (latency hides under phases A-C)
    const size_t rowoff = ((size_t)w * Dc + d) * Lc;
    const float4* xr4 = (const float4*)(x + rowoff);
    const int base = m * 8 + 2 * g;
    float4 a0 = xr4[base],       b0 = xr4[base + 1];
    float4 a1 = xr4[base + 128], b1 = xr4[base + 129];
    float4 a2 = xr4[base + 256], b2 = xr4[base + 257];
    float4 a3 = xr4[base + 384], b3 = xr4[base + 385];

    // ---- phase A: power table, thread (n, j) computes q_n^j directly
    {
        int n = tid >> 5;                // 0..15
        int j = (tid & 31) + 1;          // 1..32
        int idx = d * 16 + n;
        float a  = 1.f / (1.f + __expf(-alpha[idx]));
        float dl = 1.f / (1.f + __expf(-delta[idx]));
        float th = (1.f / (1.f + __expf(-theta[d]))) * (6.283185307179586f / 16.f);
        float phi = (float)(n + 1) * th;
        float radius = fminf(1.f - a * dl, 1.f);
        float rj = __expf((float)j * __logf(radius));   // == reference decay
        float sn, cs; __sincosf((float)j * phi, &sn, &cs);
        float pr = rj * cs, pi = rj * sn;
        qpr[n * 33 + j] = pr;
        qpi[n * 33 + j] = pi;
        if (j == 1) {
            qpr[n * 33] = 1.f; qpi[n * 33] = 0.f;
            gprs[n] = gamma_r[idx] * 0.25f * a;
            gpis[n] = gamma_i[idx] * 0.25f * a;
        }
        if (j == 32) scanw[n] = make_float2(pr, pi);
    }
    __syncthreads();

    // ---- phase B: kernel taps
    if (tid < 33) {
        float s = 0.f;
        #pragma unroll
        for (int n = 0; n < 16; ++n)
            s += gprs[n] * qpr[n * 33 + tid] - gpis[n] * qpi[n * 33 + tid];
        if (tid == 0) s += omega[d];
        kap[tid] = s;
    }
    __syncthreads();

    // ---- phase C: T/G/V A-fragments -> LDS
    if (tid < 384) {
        int mat = tid >> 7;              // 0:T 1:G 2:V
        int sub = tid & 127;
        int rt = sub >> 6, ll = sub & 63;
        int row = rt * 16 + (ll & 15);
        int kb = 8 * (ll >> 4);
        union { _Float16 h[8]; f16x8 v; } fv;
        if (mat == 0) {
            #pragma unroll
            for (int j = 0; j < 8; ++j) {
                int dlt = row - (kb + j);
                fv.h[j] = (_Float16)((dlt >= 0) ? kap[dlt] : 0.f);
            }
        } else if (mat == 1) {
            #pragma unroll
            for (int j = 0; j < 8; ++j) {
                int k = kb + j, n = k >> 1;
                float qr_ = qpr[n * 33 + row + 1], qi_ = qpi[n * 33 + row + 1];
                float gr = gprs[n], gi = gpis[n];
                fv.h[j] = (_Float16)((k & 1) ? -(gr * qi_ + gi * qr_)
                                             : (gr * qr_ - gi * qi_));
            }
        } else {
            int n = row >> 1, im = row & 1;
            #pragma unroll
            for (int j = 0; j < 8; ++j) {
                int mm = kb + j;
                fv.h[j] = (_Float16)(im ? qpi[n * 33 + 31 - mm] : qpr[n * 33 + 31 - mm]);
            }
        }
        *(f16x8*)&fragH[(mat * 128 + rt * 64 + ll) * 8] = fv.v;
    }
    __syncthreads();                     // last barrier: frags visible, tab dead

    // ================= per-wave independent section (no barriers) ========
    uint* EC = ECall + w * (64 * ECS);

    f16x8 xf0 = cvt8(a0, b0), xf1 = cvt8(a1, b1);
    f16x8 xf2 = cvt8(a2, b2), xf3 = cvt8(a3, b3);

    // ---- E = V*X (chunk end-states), pack f16 pairs into own EC slice
    {
        f16x8 va0 = frag[256 + l], va1 = frag[320 + l];
        #define EMFMA(VA, RT, TC, XF) { \
            f32x4 acc = {0.f, 0.f, 0.f, 0.f}; \
            acc = __builtin_amdgcn_mfma_f32_16x16x32_f16(VA, XF, acc, 0, 0, 0); \
            uint2 u; u.x = pkh(acc[0], acc[1]); u.y = pkh(acc[2], acc[3]); \
            *(uint2*)&EC[(TC * 16 + m) * ECS + 8 * RT + 2 * g] = u; }
        EMFMA(va0, 0, 0, xf0) EMFMA(va0, 0, 1, xf1)
        EMFMA(va0, 0, 2, xf2) EMFMA(va0, 0, 3, xf3)
        EMFMA(va1, 1, 0, xf0) EMFMA(va1, 1, 1, xf1)
        EMFMA(va1, 1, 2, xf2) EMFMA(va1, 1, 3, xf3)
        #undef EMFMA
    }

    // ---- w1 / T / G from LDS (overlap with EC write drain)
    float w1r[4], w1i[4];
    #pragma unroll
    for (int j = 0; j < 4; ++j) {
        float2 t = scanw[4 * g + j];
        w1r[j] = t.x; w1i[j] = t.y;
    }
    f16x8 ta0 = frag[l],       ta1 = frag[64 + l];
    f16x8 ga0 = frag[128 + l], ga1 = frag[192 + l];

    __builtin_amdgcn_wave_barrier();     // compiler fence only

    // ---- per tile: truncated-carry gather (running weight), then Y
    float4* or4 = (float4*)(out + rowoff);

    #pragma unroll
    for (int tc = 0; tc < 4; ++tc) {
        f16x8 xf = (tc == 0) ? xf0 : (tc == 1) ? xf1 : (tc == 2) ? xf2 : xf3;
        float cr_[4] = {0.f, 0.f, 0.f, 0.f};
        float ci_[4] = {0.f, 0.f, 0.f, 0.f};
        float kr[4] = {1.f, 1.f, 1.f, 1.f};
        float ki[4] = {0.f, 0.f, 0.f, 0.f};
        #pragma unroll
        for (int k = 1; k <= 4; ++k) {
            int c2 = tc * 16 + m - k;
            int cc = (c2 < 0) ? 0 : c2;
            uint2 e0 = *(const uint2*)&EC[cc * ECS + 4 * g];
            uint2 e1 = *(const uint2*)&EC[cc * ECS + 4 * g + 2];
            if (c2 >= 0) {
                float2 aa[4] = { upk(e0.x), upk(e0.y), upk(e1.x), upk(e1.y) };
                #pragma unroll
                for (int j = 0; j < 4; ++j) {
                    cr_[j] = fmaf(kr[j], aa[j].x, fmaf(-ki[j], aa[j].y, cr_[j]));
                    ci_[j] = fmaf(kr[j], aa[j].y, fmaf( ki[j], aa[j].x, ci_[j]));
                }
            }
            if (k < 4) {
                #pragma unroll
                for (int j = 0; j < 4; ++j) {
                    float t2 = fmaf(kr[j], w1r[j], -(ki[j] * w1i[j]));
                    ki[j] = fmaf(kr[j], w1i[j], ki[j] * w1r[j]);
                    kr[j] = t2;
                }
            }
        }
        union { h16x2 h[4]; f16x8 v; } cb;
        #pragma unroll
        for (int j = 0; j < 4; ++j)
            cb.h[j] = __builtin_amdgcn_cvt_pkrtz(cr_[j], ci_[j]);
        f32x4 y0 = {0.f, 0.f, 0.f, 0.f}, y1 = {0.f, 0.f, 0.f, 0.f};
        y0 = __builtin_amdgcn_mfma_f32_16x16x32_f16(ta0, xf,   y0, 0, 0, 0);
        y0 = __builtin_amdgcn_mfma_f32_16x16x32_f16(ga0, cb.v, y0, 0, 0, 0);
        y1 = __builtin_amdgcn_mfma_f32_16x16x32_f16(ta1, xf,   y1, 0, 0, 0);
        y1 = __builtin_amdgcn_mfma_f32_16x16x32_f16(ga1, cb.v, y1, 0, 0, 0);
        float4 o0, o1;
        o0.x = y0[0]; o0.y = y0[1]; o0.z = y0[2]; o0.w = y0[3];
        o1.x = y1[0]; o1.y = y1[1]; o1.z = y1[2]; o1.w = y1[3];
        or4[(tc * 16 + m) * 8 + g]     = o0;
        or4[(tc * 16 + m) * 8 + 4 + g] = o1;
    }
}

extern "C" void kernel_launch(void* const* d_in, const int* in_sizes, int n_in,
                              void* d_out, int out_size, void* d_ws, size_t ws_size,
                              hipStream_t stream) {
    const float* x       = (const float*)d_in[0];
    const float* alpha   = (const float*)d_in[1];
    const float* delta   = (const float*)d_in[2];
    const float* theta   = (const float*)d_in[3];
    const float* gamma_r = (const float*)d_in[4];
    const float* gamma_i = (const float*)d_in[5];
    const float* omega   = (const float*)d_in[6];
    float* out = (float*)d_out;

    ema_fused<<<Dc, 512, 0, stream>>>(x, alpha, delta, theta,
                                      gamma_r, gamma_i, omega, out);
}